// Round 7
// baseline (499.529 us; speedup 1.0000x reference)
//
// R11: R9 base (verified 398.6us) + double B-tile width in both GEMMs:
// gemm1 128x128 (accg/accu 4x4, grid x 32->16), gemm2 128x256 (acc 4x8,
// grid x 8->4). 48KB LDS, 64 MFMA/K-step: 21-43 FLOP/staged-byte vs 16.
// Fill(512MB re-poison, 77us x2/iter) identified as fixed harness overhead.
#include <hip/hip_runtime.h>
#include <stdint.h>

#define TOKS 4096
#define DIM  1024
#define HID  2048
#define OUTD 1024
#define NE   8
#define MP   9216
#define NBR  72

typedef __bf16 bf16;
typedef bf16 bf16x8 __attribute__((ext_vector_type(8)));
typedef float f32x4 __attribute__((ext_vector_type(4)));
typedef __attribute__((address_space(1))) void gvoid;
typedef __attribute__((address_space(3))) void lvoid;

// ---- workspace byte offsets ----
#define WGU_OFF  0ull                         // 64MB bf16 weights; O0/O1 bf16 alias after gemm1
#define WD_OFF   (WGU_OFF + 67108864ull)
#define XG_OFF   (WD_OFF  + 33554432ull)      // token-major: TOKS*DIM*2 = 8.4MB
#define H_OFF    (XG_OFF  + 18874368ull)      // MP*2048*2
#define TK_OFF   (H_OFF   + 37748736ull)      // MP*4
#define META_OFF (TK_OFF  + 36864ull)         // table NBR ints
#define T2S_OFF  (META_OFF + 1024ull)         // TOKS*2 ints
#define O0_OFF   WGU_OFF
#define O1_OFF   (WGU_OFF + 18874368ull)

__device__ __forceinline__ unsigned short f2bf(float f) {
  union { float f; unsigned u; } v; v.f = f;
  unsigned r = (v.u + 0x7FFFu + ((v.u >> 16) & 1u)) >> 16;
  return (unsigned short)r;
}
__device__ __forceinline__ float bf2f(unsigned short h) {
  union { unsigned u; float f; } v; v.u = ((unsigned)h) << 16; return v.f;
}
__device__ __forceinline__ unsigned pack2(float a, float b) {
  return (unsigned)f2bf(a) | ((unsigned)f2bf(b) << 16);
}
__device__ __forceinline__ void cp16(const void* g, void* l) {
  __builtin_amdgcn_global_load_lds((gvoid*)(void*)g, (lvoid*)l, 16, 0, 0);
}

// ---------- fused routing (block 0) + Wgu convert + X convert (token-major) ----------
#define CONVB_GU (NE * 2 * HID * DIM / 4 / 1024)   // 8192
#define CONVB_X  (TOKS * DIM / 4 / 1024)           // 1024
__global__ __launch_bounds__(1024) void route_conv_kernel(
    const int* __restrict__ idx, int* __restrict__ table,
    int* __restrict__ slot_token, int* __restrict__ tok2slot,
    const float4* __restrict__ srcGu, uint2* __restrict__ dstGu,
    const float4* __restrict__ srcX, uint2* __restrict__ dstXg) {
  if (blockIdx.x != 0) {
    int b = (int)blockIdx.x - 1;
    const float4* src; uint2* dst; int i;
    if (b < CONVB_GU) { i = b * 1024 + threadIdx.x; src = srcGu; dst = dstGu; }
    else              { i = (b - CONVB_GU) * 1024 + threadIdx.x; src = srcX; dst = dstXg; }
    float4 v = src[i];
    uint2 o; o.x = pack2(v.x, v.y); o.y = pack2(v.z, v.w);
    dst[i] = o;
    return;
  }
  // ---- routing: one 1024-thread block ----
  __shared__ int cnt[NE], offs[NE], cur[NE];
  const int tid = threadIdx.x, lane = tid & 63;
  for (int i = tid; i < MP; i += 1024) slot_token[i] = -1;
  if (tid < NE) cnt[tid] = 0;
  __syncthreads();
  int myE[8];
#pragma unroll
  for (int c = 0; c < 8; ++c) myE[c] = idx[c * 1024 + tid];
#pragma unroll
  for (int c = 0; c < 8; ++c) {
    int e = myE[c];
#pragma unroll
    for (int ex = 0; ex < NE; ++ex) {
      unsigned long long m = __ballot(e == ex);
      if (lane == 0 && m) atomicAdd(&cnt[ex], __popcll(m));
    }
  }
  __syncthreads();
  if (tid == 0) {
    int cum = 0;
    for (int e = 0; e < NE; ++e) {
      offs[e] = cum; cur[e] = 0;
      int nb = (cnt[e] + 127) >> 7;
      int bb = cum >> 7;
      for (int b = 0; b < nb; ++b) table[bb + b] = e;
      cum += nb << 7;
    }
    for (int b = cum >> 7; b < NBR; ++b) table[b] = -1;
  }
  __syncthreads();
#pragma unroll
  for (int c = 0; c < 8; ++c) {
    int e = myE[c];
    int pos = 0;
#pragma unroll
    for (int ex = 0; ex < NE; ++ex) {
      unsigned long long m = __ballot(e == ex);
      if (e == ex) {
        int rank = __popcll(m & ((1ull << lane) - 1ull));
        int leader = __ffsll(m) - 1;
        int base = 0;
        if (lane == leader) base = atomicAdd(&cur[ex], __popcll(m));
        base = __shfl(base, leader);
        pos = offs[ex] + base + rank;
      }
    }
    slot_token[pos] = (c * 1024 + tid) >> 1;
    tok2slot[c * 1024 + tid] = pos;
  }
}

__global__ void combine_kernel(const unsigned short* __restrict__ O0,
                               const unsigned short* __restrict__ O1,
                               const int* __restrict__ tok2slot,
                               const float* __restrict__ wts, float4* __restrict__ out) {
  int t = blockIdx.x, c = threadIdx.x;   // 4096 x 256; 4 cols/thread
  int s0 = tok2slot[2 * t], s1 = tok2slot[2 * t + 1];
  float w0 = wts[2 * t], w1 = wts[2 * t + 1];
  uint2 a0 = ((const uint2*)(O0 + (size_t)s0 * OUTD))[c];
  uint2 b0 = ((const uint2*)(O1 + (size_t)s0 * OUTD))[c];
  uint2 a1 = ((const uint2*)(O0 + (size_t)s1 * OUTD))[c];
  uint2 b1 = ((const uint2*)(O1 + (size_t)s1 * OUTD))[c];
  float4 o;
  o.x = w0 * (bf2f(a0.x & 0xFFFF) + bf2f(b0.x & 0xFFFF)) + w1 * (bf2f(a1.x & 0xFFFF) + bf2f(b1.x & 0xFFFF));
  o.y = w0 * (bf2f(a0.x >> 16)    + bf2f(b0.x >> 16))    + w1 * (bf2f(a1.x >> 16)    + bf2f(b1.x >> 16));
  o.z = w0 * (bf2f(a0.y & 0xFFFF) + bf2f(b0.y & 0xFFFF)) + w1 * (bf2f(a1.y & 0xFFFF) + bf2f(b1.y & 0xFFFF));
  o.w = w0 * (bf2f(a0.y >> 16)    + bf2f(b0.y >> 16))    + w1 * (bf2f(a1.y >> 16)    + bf2f(b1.y >> 16));
  out[(size_t)t * (OUTD / 4) + c] = o;
}

// ---------- GEMM1: h = silu(Xg*Wg^T) * (Xg*Wu^T), BK=64, 16x16x32, 128x128 tile ----------
// grid (24, 72): x<16 GEMM tiles (128 h-cols each); x>=16 Wd convert (overlapped)
#define WD_N4 (NE * OUTD * HID / 4)     // 4194304 float4
#define CVT_NB 576                      // 8 x 72 convert blocks
__global__ __launch_bounds__(256) void gemm1_kernel(
    const unsigned short* __restrict__ Xg,   // [TOKS, DIM] token-major
    const unsigned short* __restrict__ Wgu,  // [NE, 2*HID, DIM]
    unsigned short* __restrict__ Hbuf,       // [MP, HID] slot-major
    const int* __restrict__ table,
    const int* __restrict__ slot_token,
    const float4* __restrict__ srcD, uint2* __restrict__ dstD) {
  if (blockIdx.x >= 16) {
    // ---- Wd convert, grid-stride over 4.2M float4 (~100MB traffic) ----
    const int cid = ((int)blockIdx.x - 16) + 8 * (int)blockIdx.y;   // 0..575
    const int NT = CVT_NB * 256;
    for (int i = cid * 256 + (int)threadIdx.x; i < WD_N4; i += NT) {
      float4 v = srcD[i];
      uint2 o; o.x = pack2(v.x, v.y); o.y = pack2(v.z, v.w);
      dstD[i] = o;
    }
    return;
  }
  int e = table[blockIdx.y];
  if (e < 0) return;
  const int tid = threadIdx.x;
  const int lane = tid & 63, wave = tid >> 6;
  const int wm = wave >> 1, wn = wave & 1;
  const int lr = lane & 15, quad = lane >> 4;

  __shared__ bf16 As[128 * 64];
  __shared__ bf16 Bg[128 * 64];
  __shared__ bf16 Bu[128 * 64];

  // slot->token row bases for the 4 rows this thread stages (kt-invariant)
  const int r0 = tid >> 3;                       // 0..31
  size_t abase[4];
#pragma unroll
  for (int i = 0; i < 4; ++i) {
    int t = slot_token[blockIdx.y * 128 + i * 32 + r0];
    if (t < 0) t = 0;                            // pad slot: alias token 0 (never combined)
    abase[i] = (size_t)t * DIM;
  }

  const unsigned short* Wg_base = Wgu + (size_t)e * 2 * HID * DIM + (size_t)(blockIdx.x * 128) * DIM;
  const unsigned short* Wu_base = Wg_base + (size_t)HID * DIM;

  f32x4 accg[4][4] = {}; f32x4 accu[4][4] = {};

  for (int kt = 0; kt < DIM / 64; ++kt) {   // 16 iters
    const int kb = kt * 64;
#pragma unroll
    for (int i = 0; i < 4; ++i) {
      int s = i * 256 + tid, row = s >> 3, pc = s & 7, gc = pc ^ (row & 7);
      cp16(Xg + abase[i] + kb + gc * 8, (void*)(As + row * 64 + pc * 8));
      cp16(Wg_base + (size_t)row * DIM + kb + gc * 8, (void*)(Bg + row * 64 + pc * 8));
      cp16(Wu_base + (size_t)row * DIM + kb + gc * 8, (void*)(Bu + row * 64 + pc * 8));
    }
    __syncthreads();
#pragma unroll
    for (int ks = 0; ks < 2; ++ks) {
      bf16x8 a[4], bg[4], bu[4];
#pragma unroll
      for (int i = 0; i < 4; ++i) {
        int row = wm * 64 + i * 16 + lr;
        int pc = (ks * 4 + quad) ^ (row & 7);
        a[i] = *(const bf16x8*)(As + row * 64 + pc * 8);
      }
#pragma unroll
      for (int j = 0; j < 4; ++j) {
        int row = wn * 64 + j * 16 + lr;
        int pc = (ks * 4 + quad) ^ (row & 7);
        bg[j] = *(const bf16x8*)(Bg + row * 64 + pc * 8);
        bu[j] = *(const bf16x8*)(Bu + row * 64 + pc * 8);
      }
#pragma unroll
      for (int i = 0; i < 4; ++i)
#pragma unroll
        for (int j = 0; j < 4; ++j) {
          accg[i][j] = __builtin_amdgcn_mfma_f32_16x16x32_bf16(a[i], bg[j], accg[i][j], 0, 0, 0);
          accu[i][j] = __builtin_amdgcn_mfma_f32_16x16x32_bf16(a[i], bu[j], accu[i][j], 0, 0, 0);
        }
    }
    __syncthreads();
  }

  const int rowBase = blockIdx.y * 128 + wm * 64;
  const int colBase = blockIdx.x * 128 + wn * 64;
#pragma unroll
  for (int i = 0; i < 4; ++i)
#pragma unroll
    for (int r = 0; r < 4; ++r) {
      int row = rowBase + i * 16 + quad * 4 + r;
#pragma unroll
      for (int j = 0; j < 4; ++j) {
        float g = accg[i][j][r], u = accu[i][j][r];
        float s = g / (1.0f + __expf(-g));
        Hbuf[(size_t)row * HID + colBase + j * 16 + lr] = f2bf(s * u);
      }
    }
}

// ---------- GEMM2: O[kslice][slot] = H(kslice)*Wd^T, BK=64, 128x256 tile, K-split x2 ----------
// grid (4, 72, 2)
__global__ __launch_bounds__(256) void gemm2_kernel(
    const unsigned short* __restrict__ Hbuf, // [MP, HID]
    const unsigned short* __restrict__ Wd,   // [NE, OUTD, HID]
    unsigned short* __restrict__ O0,         // [MP, OUTD] bf16 partial
    unsigned short* __restrict__ O1,
    const int* __restrict__ table) {
  int e = table[blockIdx.y];
  if (e < 0) return;
  const int tid = threadIdx.x;
  const int lane = tid & 63, wave = tid >> 6;
  const int wm = wave >> 1, wn = wave & 1;
  const int lr = lane & 15, quad = lane >> 4;
  const int kslice = blockIdx.z;

  __shared__ bf16 As[128 * 64];
  __shared__ bf16 Bs[256 * 64];

  const unsigned short* A_base = Hbuf + (size_t)blockIdx.y * 128 * HID + kslice * (HID / 2);
  const unsigned short* B_base = Wd + (size_t)e * OUTD * HID + (size_t)(blockIdx.x * 256) * HID
                               + kslice * (HID / 2);

  f32x4 acc[4][8] = {};

  for (int kt = 0; kt < (HID / 2) / 64; ++kt) {   // 16 iters
    const int kb = kt * 64;
#pragma unroll
    for (int i = 0; i < 4; ++i) {
      int s = i * 256 + tid, row = s >> 3, pc = s & 7, gc = pc ^ (row & 7);
      cp16(A_base + (size_t)row * HID + kb + gc * 8, (void*)(As + row * 64 + pc * 8));
    }
#pragma unroll
    for (int i = 0; i < 8; ++i) {
      int s = i * 256 + tid, row = s >> 3, pc = s & 7, gc = pc ^ (row & 7);
      cp16(B_base + (size_t)row * HID + kb + gc * 8, (void*)(Bs + row * 64 + pc * 8));
    }
    __syncthreads();
#pragma unroll
    for (int ks = 0; ks < 2; ++ks) {
      bf16x8 a[4], b[8];
#pragma unroll
      for (int i = 0; i < 4; ++i) {
        int row = wm * 64 + i * 16 + lr;
        int pc = (ks * 4 + quad) ^ (row & 7);
        a[i] = *(const bf16x8*)(As + row * 64 + pc * 8);
      }
#pragma unroll
      for (int j = 0; j < 8; ++j) {
        int row = wn * 128 + j * 16 + lr;
        int pc = (ks * 4 + quad) ^ (row & 7);
        b[j] = *(const bf16x8*)(Bs + row * 64 + pc * 8);
      }
#pragma unroll
      for (int i = 0; i < 4; ++i)
#pragma unroll
        for (int j = 0; j < 8; ++j)
          acc[i][j] = __builtin_amdgcn_mfma_f32_16x16x32_bf16(a[i], b[j], acc[i][j], 0, 0, 0);
    }
    __syncthreads();
  }

  unsigned short* O = kslice ? O1 : O0;
  const int rowBase = blockIdx.y * 128 + wm * 64;
  const int colBase = blockIdx.x * 256 + wn * 128;
#pragma unroll
  for (int i = 0; i < 4; ++i)
#pragma unroll
    for (int r = 0; r < 4; ++r) {
      int row = rowBase + i * 16 + quad * 4 + r;
      unsigned short* Orow = O + (size_t)row * OUTD + colBase;
#pragma unroll
      for (int j = 0; j < 8; ++j)
        Orow[j * 16 + lr] = f2bf(acc[i][j][r]);
    }
}

extern "C" void kernel_launch(void* const* d_in, const int* in_sizes, int n_in,
                              void* d_out, int out_size, void* d_ws, size_t ws_size,
                              hipStream_t stream) {
  const float* X     = (const float*)d_in[0];
  const int*   idx   = (const int*)d_in[1];
  const float* wts   = (const float*)d_in[2];
  const float* WguF  = (const float*)d_in[3];
  const float* WdF   = (const float*)d_in[4];
  float* out = (float*)d_out;

  char* base = (char*)d_ws;
  unsigned short* Wgu = (unsigned short*)(base + WGU_OFF);
  unsigned short* Wd  = (unsigned short*)(base + WD_OFF);
  unsigned short* Xg  = (unsigned short*)(base + XG_OFF);
  unsigned short* Hb  = (unsigned short*)(base + H_OFF);
  unsigned short* O0  = (unsigned short*)(base + O0_OFF);   // alias Wgu (dead after gemm1)
  unsigned short* O1  = (unsigned short*)(base + O1_OFF);
  int* slot_token = (int*)(base + TK_OFF);
  int* table      = (int*)(base + META_OFF);
  int* tok2slot   = (int*)(base + T2S_OFF);

  route_conv_kernel<<<1 + CONVB_GU + CONVB_X, 1024, 0, stream>>>(idx, table, slot_token, tok2slot,
      (const float4*)WguF, (uint2*)Wgu, (const float4*)X, (uint2*)Xg);
  gemm1_kernel<<<dim3(24, NBR), 256, 0, stream>>>(Xg, Wgu, Hb, table, slot_token,
      (const float4*)WdF, (uint2*)Wd);
  gemm2_kernel<<<dim3(4, NBR, 2), 256, 0, stream>>>(Hb, Wd, O0, O1, table);
  combine_kernel<<<TOKS, 256, 0, stream>>>(O0, O1, tok2slot, wts, (float4*)out);
}

// Round 8
// 442.590 us; speedup vs baseline: 1.1287x; 1.1287x over previous
//
// R12: R9 base + BK=32 double-buffered pipeline at CONSTANT 32KB LDS in both
// GEMMs (R6/R11 lesson: never trade occupancy for intra-block overlap; this
// dbuf keeps 2x16KB = same footprint). One barrier per K-step, loads issued a
// full compute-phase early. Swizzle for 64B rows: p = q ^ ((row>>1)&3) -> 2-way
// (free). Routing/converts/combine/geometry identical to R9 (verified 398.6).
#include <hip/hip_runtime.h>
#include <stdint.h>

#define TOKS 4096
#define DIM  1024
#define HID  2048
#define OUTD 1024
#define NE   8
#define MP   9216
#define NBR  72

typedef __bf16 bf16;
typedef bf16 bf16x8 __attribute__((ext_vector_type(8)));
typedef float f32x4 __attribute__((ext_vector_type(4)));
typedef __attribute__((address_space(1))) void gvoid;
typedef __attribute__((address_space(3))) void lvoid;

// ---- workspace byte offsets ----
#define WGU_OFF  0ull                         // 64MB bf16 weights; O0/O1 bf16 alias after gemm1
#define WD_OFF   (WGU_OFF + 67108864ull)
#define XG_OFF   (WD_OFF  + 33554432ull)      // token-major: TOKS*DIM*2 = 8.4MB
#define H_OFF    (XG_OFF  + 18874368ull)      // MP*2048*2
#define TK_OFF   (H_OFF   + 37748736ull)      // MP*4
#define META_OFF (TK_OFF  + 36864ull)         // table NBR ints
#define T2S_OFF  (META_OFF + 1024ull)         // TOKS*2 ints
#define O0_OFF   WGU_OFF
#define O1_OFF   (WGU_OFF + 18874368ull)

__device__ __forceinline__ unsigned short f2bf(float f) {
  union { float f; unsigned u; } v; v.f = f;
  unsigned r = (v.u + 0x7FFFu + ((v.u >> 16) & 1u)) >> 16;
  return (unsigned short)r;
}
__device__ __forceinline__ float bf2f(unsigned short h) {
  union { unsigned u; float f; } v; v.u = ((unsigned)h) << 16; return v.f;
}
__device__ __forceinline__ unsigned pack2(float a, float b) {
  return (unsigned)f2bf(a) | ((unsigned)f2bf(b) << 16);
}
__device__ __forceinline__ void cp16(const void* g, void* l) {
  __builtin_amdgcn_global_load_lds((gvoid*)(void*)g, (lvoid*)l, 16, 0, 0);
}

// ---------- fused routing (block 0) + Wgu convert + X convert (token-major) ----------
#define CONVB_GU (NE * 2 * HID * DIM / 4 / 1024)   // 8192
#define CONVB_X  (TOKS * DIM / 4 / 1024)           // 1024
__global__ __launch_bounds__(1024) void route_conv_kernel(
    const int* __restrict__ idx, int* __restrict__ table,
    int* __restrict__ slot_token, int* __restrict__ tok2slot,
    const float4* __restrict__ srcGu, uint2* __restrict__ dstGu,
    const float4* __restrict__ srcX, uint2* __restrict__ dstXg) {
  if (blockIdx.x != 0) {
    int b = (int)blockIdx.x - 1;
    const float4* src; uint2* dst; int i;
    if (b < CONVB_GU) { i = b * 1024 + threadIdx.x; src = srcGu; dst = dstGu; }
    else              { i = (b - CONVB_GU) * 1024 + threadIdx.x; src = srcX; dst = dstXg; }
    float4 v = src[i];
    uint2 o; o.x = pack2(v.x, v.y); o.y = pack2(v.z, v.w);
    dst[i] = o;
    return;
  }
  // ---- routing: one 1024-thread block ----
  __shared__ int cnt[NE], offs[NE], cur[NE];
  const int tid = threadIdx.x, lane = tid & 63;
  for (int i = tid; i < MP; i += 1024) slot_token[i] = -1;
  if (tid < NE) cnt[tid] = 0;
  __syncthreads();
  int myE[8];
#pragma unroll
  for (int c = 0; c < 8; ++c) myE[c] = idx[c * 1024 + tid];
#pragma unroll
  for (int c = 0; c < 8; ++c) {
    int e = myE[c];
#pragma unroll
    for (int ex = 0; ex < NE; ++ex) {
      unsigned long long m = __ballot(e == ex);
      if (lane == 0 && m) atomicAdd(&cnt[ex], __popcll(m));
    }
  }
  __syncthreads();
  if (tid == 0) {
    int cum = 0;
    for (int e = 0; e < NE; ++e) {
      offs[e] = cum; cur[e] = 0;
      int nb = (cnt[e] + 127) >> 7;
      int bb = cum >> 7;
      for (int b = 0; b < nb; ++b) table[bb + b] = e;
      cum += nb << 7;
    }
    for (int b = cum >> 7; b < NBR; ++b) table[b] = -1;
  }
  __syncthreads();
#pragma unroll
  for (int c = 0; c < 8; ++c) {
    int e = myE[c];
    int pos = 0;
#pragma unroll
    for (int ex = 0; ex < NE; ++ex) {
      unsigned long long m = __ballot(e == ex);
      if (e == ex) {
        int rank = __popcll(m & ((1ull << lane) - 1ull));
        int leader = __ffsll(m) - 1;
        int base = 0;
        if (lane == leader) base = atomicAdd(&cur[ex], __popcll(m));
        base = __shfl(base, leader);
        pos = offs[ex] + base + rank;
      }
    }
    slot_token[pos] = (c * 1024 + tid) >> 1;
    tok2slot[c * 1024 + tid] = pos;
  }
}

__global__ void combine_kernel(const unsigned short* __restrict__ O0,
                               const unsigned short* __restrict__ O1,
                               const int* __restrict__ tok2slot,
                               const float* __restrict__ wts, float4* __restrict__ out) {
  int t = blockIdx.x, c = threadIdx.x;   // 4096 x 256; 4 cols/thread
  int s0 = tok2slot[2 * t], s1 = tok2slot[2 * t + 1];
  float w0 = wts[2 * t], w1 = wts[2 * t + 1];
  uint2 a0 = ((const uint2*)(O0 + (size_t)s0 * OUTD))[c];
  uint2 b0 = ((const uint2*)(O1 + (size_t)s0 * OUTD))[c];
  uint2 a1 = ((const uint2*)(O0 + (size_t)s1 * OUTD))[c];
  uint2 b1 = ((const uint2*)(O1 + (size_t)s1 * OUTD))[c];
  float4 o;
  o.x = w0 * (bf2f(a0.x & 0xFFFF) + bf2f(b0.x & 0xFFFF)) + w1 * (bf2f(a1.x & 0xFFFF) + bf2f(b1.x & 0xFFFF));
  o.y = w0 * (bf2f(a0.x >> 16)    + bf2f(b0.x >> 16))    + w1 * (bf2f(a1.x >> 16)    + bf2f(b1.x >> 16));
  o.z = w0 * (bf2f(a0.y & 0xFFFF) + bf2f(b0.y & 0xFFFF)) + w1 * (bf2f(a1.y & 0xFFFF) + bf2f(b1.y & 0xFFFF));
  o.w = w0 * (bf2f(a0.y >> 16)    + bf2f(b0.y >> 16))    + w1 * (bf2f(a1.y >> 16)    + bf2f(b1.y >> 16));
  out[(size_t)t * (OUTD / 4) + c] = o;
}

// ---------- GEMM1: h = silu(Xg*Wg^T) * (Xg*Wu^T), BK=32 dbuf, 16x16x32 ----------
// grid (40, 72): x<32 = GEMM tiles (64 h-cols); x>=32 = Wd convert (overlapped)
#define WD_N4 (NE * OUTD * HID / 4)     // 4194304 float4
#define CVT_NB 576                      // 8 x 72 convert blocks
__global__ __launch_bounds__(256) void gemm1_kernel(
    const unsigned short* __restrict__ Xg,   // [TOKS, DIM] token-major
    const unsigned short* __restrict__ Wgu,  // [NE, 2*HID, DIM]
    unsigned short* __restrict__ Hbuf,       // [MP, HID] slot-major
    const int* __restrict__ table,
    const int* __restrict__ slot_token,
    const float4* __restrict__ srcD, uint2* __restrict__ dstD) {
  if (blockIdx.x >= 32) {
    const int cid = ((int)blockIdx.x - 32) + 8 * (int)blockIdx.y;   // 0..575
    const int NT = CVT_NB * 256;
    for (int i = cid * 256 + (int)threadIdx.x; i < WD_N4; i += NT) {
      float4 v = srcD[i];
      uint2 o; o.x = pack2(v.x, v.y); o.y = pack2(v.z, v.w);
      dstD[i] = o;
    }
    return;
  }
  int e = table[blockIdx.y];
  if (e < 0) return;
  const int tid = threadIdx.x;
  const int lane = tid & 63, wave = tid >> 6;
  const int wm = wave >> 1, wn = wave & 1;
  const int lr = lane & 15, quad = lane >> 4;

  __shared__ bf16 As[2][128 * 32];
  __shared__ bf16 Bg[2][64 * 32];
  __shared__ bf16 Bu[2][64 * 32];

  // slot->token row bases for the 2 A-rows this thread stages (kt-invariant)
  const int r0 = tid >> 2;                       // 0..63 (4 threads/row)
  size_t abase[2];
#pragma unroll
  for (int i = 0; i < 2; ++i) {
    int t = slot_token[blockIdx.y * 128 + i * 64 + r0];
    if (t < 0) t = 0;                            // pad slot: alias token 0 (never combined)
    abase[i] = (size_t)t * DIM;
  }

  const unsigned short* Wg_base = Wgu + (size_t)e * 2 * HID * DIM + (size_t)(blockIdx.x * 64) * DIM;
  const unsigned short* Wu_base = Wg_base + (size_t)HID * DIM;

  f32x4 accg[4][2] = {}; f32x4 accu[4][2] = {};

  auto stage = [&](bf16* as, bf16* bg, bf16* bu, int kt) {
    const int kb = kt * 32;
#pragma unroll
    for (int i = 0; i < 2; ++i) {
      int s = i * 256 + tid, row = s >> 2, p = s & 3, gc = p ^ ((row >> 1) & 3);
      cp16(Xg + abase[i] + kb + gc * 8, (void*)(as + row * 32 + p * 8));
    }
    {
      int s = tid, row = s >> 2, p = s & 3, gc = p ^ ((row >> 1) & 3);
      cp16(Wg_base + (size_t)row * DIM + kb + gc * 8, (void*)(bg + row * 32 + p * 8));
      cp16(Wu_base + (size_t)row * DIM + kb + gc * 8, (void*)(bu + row * 32 + p * 8));
    }
  };

  auto compute = [&](const bf16* as, const bf16* bg, const bf16* bu) {
    bf16x8 a[4], g[2], u[2];
#pragma unroll
    for (int i = 0; i < 4; ++i) {
      int row = wm * 64 + i * 16 + lr;
      int p = quad ^ ((row >> 1) & 3);
      a[i] = *(const bf16x8*)(as + row * 32 + p * 8);
    }
#pragma unroll
    for (int j = 0; j < 2; ++j) {
      int row = wn * 32 + j * 16 + lr;
      int p = quad ^ ((row >> 1) & 3);
      g[j] = *(const bf16x8*)(bg + row * 32 + p * 8);
      u[j] = *(const bf16x8*)(bu + row * 32 + p * 8);
    }
#pragma unroll
    for (int i = 0; i < 4; ++i)
#pragma unroll
      for (int j = 0; j < 2; ++j) {
        accg[i][j] = __builtin_amdgcn_mfma_f32_16x16x32_bf16(a[i], g[j], accg[i][j], 0, 0, 0);
        accu[i][j] = __builtin_amdgcn_mfma_f32_16x16x32_bf16(a[i], u[j], accu[i][j], 0, 0, 0);
      }
  };

  stage(As[0], Bg[0], Bu[0], 0);
  __syncthreads();
#pragma unroll 1
  for (int kt = 0; kt < DIM / 32; kt += 2) {   // 32 K-steps, 2 per iter
    stage(As[1], Bg[1], Bu[1], kt + 1);        // issue next BEFORE compute
    compute(As[0], Bg[0], Bu[0]);
    __syncthreads();
    if (kt + 2 < DIM / 32) stage(As[0], Bg[0], Bu[0], kt + 2);
    compute(As[1], Bg[1], Bu[1]);
    __syncthreads();
  }

  const int rowBase = blockIdx.y * 128 + wm * 64;
  const int colBase = blockIdx.x * 64 + wn * 32;
#pragma unroll
  for (int i = 0; i < 4; ++i)
#pragma unroll
    for (int r = 0; r < 4; ++r) {
      int row = rowBase + i * 16 + quad * 4 + r;
#pragma unroll
      for (int j = 0; j < 2; ++j) {
        float g = accg[i][j][r], u = accu[i][j][r];
        float s = g / (1.0f + __expf(-g));
        Hbuf[(size_t)row * HID + colBase + j * 16 + lr] = f2bf(s * u);
      }
    }
}

// ---------- GEMM2: O[kslice][slot] = H(kslice)*Wd^T, BK=32 dbuf, K-split x2 ----------
// grid (8, 72, 2)
__global__ __launch_bounds__(256) void gemm2_kernel(
    const unsigned short* __restrict__ Hbuf, // [MP, HID]
    const unsigned short* __restrict__ Wd,   // [NE, OUTD, HID]
    unsigned short* __restrict__ O0,         // [MP, OUTD] bf16 partial
    unsigned short* __restrict__ O1,
    const int* __restrict__ table) {
  int e = table[blockIdx.y];
  if (e < 0) return;
  const int tid = threadIdx.x;
  const int lane = tid & 63, wave = tid >> 6;
  const int wm = wave >> 1, wn = wave & 1;
  const int lr = lane & 15, quad = lane >> 4;
  const int kslice = blockIdx.z;

  __shared__ bf16 As[2][128 * 32];
  __shared__ bf16 Bs[2][128 * 32];

  const unsigned short* A_base = Hbuf + (size_t)blockIdx.y * 128 * HID + kslice * (HID / 2);
  const unsigned short* B_base = Wd + (size_t)e * OUTD * HID + (size_t)(blockIdx.x * 128) * HID
                               + kslice * (HID / 2);

  f32x4 acc[4][4] = {};

  auto stage = [&](bf16* as, bf16* bs, int kt) {
    const int kb = kt * 32;
#pragma unroll
    for (int i = 0; i < 2; ++i) {
      int s = i * 256 + tid, row = s >> 2, p = s & 3, gc = p ^ ((row >> 1) & 3);
      cp16(A_base + (size_t)row * HID + kb + gc * 8, (void*)(as + row * 32 + p * 8));
      cp16(B_base + (size_t)row * HID + kb + gc * 8, (void*)(bs + row * 32 + p * 8));
    }
  };

  auto compute = [&](const bf16* as, const bf16* bs) {
    bf16x8 a[4], b[4];
#pragma unroll
    for (int i = 0; i < 4; ++i) {
      int row = wm * 64 + i * 16 + lr;
      int p = quad ^ ((row >> 1) & 3);
      a[i] = *(const bf16x8*)(as + row * 32 + p * 8);
    }
#pragma unroll
    for (int j = 0; j < 4; ++j) {
      int row = wn * 64 + j * 16 + lr;
      int p = quad ^ ((row >> 1) & 3);
      b[j] = *(const bf16x8*)(bs + row * 32 + p * 8);
    }
#pragma unroll
    for (int i = 0; i < 4; ++i)
#pragma unroll
      for (int j = 0; j < 4; ++j)
        acc[i][j] = __builtin_amdgcn_mfma_f32_16x16x32_bf16(a[i], b[j], acc[i][j], 0, 0, 0);
  };

  stage(As[0], Bs[0], 0);
  __syncthreads();
#pragma unroll 1
  for (int kt = 0; kt < (HID / 2) / 32; kt += 2) {   // 32 K-steps, 2 per iter
    stage(As[1], Bs[1], kt + 1);
    compute(As[0], Bs[0]);
    __syncthreads();
    if (kt + 2 < (HID / 2) / 32) stage(As[0], Bs[0], kt + 2);
    compute(As[1], Bs[1]);
    __syncthreads();
  }

  unsigned short* O = kslice ? O1 : O0;
  const int rowBase = blockIdx.y * 128 + wm * 64;
  const int colBase = blockIdx.x * 128 + wn * 64;
#pragma unroll
  for (int i = 0; i < 4; ++i)
#pragma unroll
    for (int r = 0; r < 4; ++r) {
      int row = rowBase + i * 16 + quad * 4 + r;
      unsigned short* Orow = O + (size_t)row * OUTD + colBase;
#pragma unroll
      for (int j = 0; j < 4; ++j)
        Orow[j * 16 + lr] = f2bf(acc[i][j][r]);
    }
}

extern "C" void kernel_launch(void* const* d_in, const int* in_sizes, int n_in,
                              void* d_out, int out_size, void* d_ws, size_t ws_size,
                              hipStream_t stream) {
  const float* X     = (const float*)d_in[0];
  const int*   idx   = (const int*)d_in[1];
  const float* wts   = (const float*)d_in[2];
  const float* WguF  = (const float*)d_in[3];
  const float* WdF   = (const float*)d_in[4];
  float* out = (float*)d_out;

  char* base = (char*)d_ws;
  unsigned short* Wgu = (unsigned short*)(base + WGU_OFF);
  unsigned short* Wd  = (unsigned short*)(base + WD_OFF);
  unsigned short* Xg  = (unsigned short*)(base + XG_OFF);
  unsigned short* Hb  = (unsigned short*)(base + H_OFF);
  unsigned short* O0  = (unsigned short*)(base + O0_OFF);   // alias Wgu (dead after gemm1)
  unsigned short* O1  = (unsigned short*)(base + O1_OFF);
  int* slot_token = (int*)(base + TK_OFF);
  int* table      = (int*)(base + META_OFF);
  int* tok2slot   = (int*)(base + T2S_OFF);

  route_conv_kernel<<<1 + CONVB_GU + CONVB_X, 1024, 0, stream>>>(idx, table, slot_token, tok2slot,
      (const float4*)WguF, (uint2*)Wgu, (const float4*)X, (uint2*)Xg);
  gemm1_kernel<<<dim3(40, NBR), 256, 0, stream>>>(Xg, Wgu, Hb, table, slot_token,
      (const float4*)WdF, (uint2*)Wd);
  gemm2_kernel<<<dim3(8, NBR, 2), 256, 0, stream>>>(Hb, Wd, O0, O1, table);
  combine_kernel<<<TOKS, 256, 0, stream>>>(O0, O1, tok2slot, wts, (float4*)out);
}

// Round 11
// 399.779 us; speedup vs baseline: 1.2495x; 1.1071x over previous
//
// R14 = exact R9 (best verified: 398.6us). R13's combine-fusion abandoned
// after 4 consecutive container failures on that source (source-correlated;
// suspect atomic-scatter/d_out multi-writer vs graph capture). Ladder:
// 435.8 -> 434.4 -> 411.4 -> 406.3 -> 398.6. gemm1 at m97-structure ceiling
// (MfmaUtil 28.6%, 3 pipelining variants all regressed); ~150us of dur_us is
// harness fill/overhead outside kernel control.
#include <hip/hip_runtime.h>
#include <stdint.h>

#define TOKS 4096
#define DIM  1024
#define HID  2048
#define OUTD 1024
#define NE   8
#define MP   9216
#define NBR  72

typedef __bf16 bf16;
typedef bf16 bf16x8 __attribute__((ext_vector_type(8)));
typedef float f32x4 __attribute__((ext_vector_type(4)));
typedef __attribute__((address_space(1))) void gvoid;
typedef __attribute__((address_space(3))) void lvoid;

// ---- workspace byte offsets ----
#define WGU_OFF  0ull                         // 64MB bf16 weights; O0/O1 bf16 alias after gemm1
#define WD_OFF   (WGU_OFF + 67108864ull)
#define XG_OFF   (WD_OFF  + 33554432ull)      // token-major: TOKS*DIM*2 = 8.4MB
#define H_OFF    (XG_OFF  + 18874368ull)      // MP*2048*2
#define TK_OFF   (H_OFF   + 37748736ull)      // MP*4
#define META_OFF (TK_OFF  + 36864ull)         // table NBR ints
#define T2S_OFF  (META_OFF + 1024ull)         // TOKS*2 ints
#define O0_OFF   WGU_OFF
#define O1_OFF   (WGU_OFF + 18874368ull)

__device__ __forceinline__ unsigned short f2bf(float f) {
  union { float f; unsigned u; } v; v.f = f;
  unsigned r = (v.u + 0x7FFFu + ((v.u >> 16) & 1u)) >> 16;
  return (unsigned short)r;
}
__device__ __forceinline__ float bf2f(unsigned short h) {
  union { unsigned u; float f; } v; v.u = ((unsigned)h) << 16; return v.f;
}
__device__ __forceinline__ unsigned pack2(float a, float b) {
  return (unsigned)f2bf(a) | ((unsigned)f2bf(b) << 16);
}
__device__ __forceinline__ void cp16(const void* g, void* l) {
  __builtin_amdgcn_global_load_lds((gvoid*)(void*)g, (lvoid*)l, 16, 0, 0);
}

// ---------- fused routing (block 0) + Wgu convert + X convert (token-major) ----------
#define CONVB_GU (NE * 2 * HID * DIM / 4 / 1024)   // 8192
#define CONVB_X  (TOKS * DIM / 4 / 1024)           // 1024
__global__ __launch_bounds__(1024) void route_conv_kernel(
    const int* __restrict__ idx, int* __restrict__ table,
    int* __restrict__ slot_token, int* __restrict__ tok2slot,
    const float4* __restrict__ srcGu, uint2* __restrict__ dstGu,
    const float4* __restrict__ srcX, uint2* __restrict__ dstXg) {
  if (blockIdx.x != 0) {
    int b = (int)blockIdx.x - 1;
    const float4* src; uint2* dst; int i;
    if (b < CONVB_GU) { i = b * 1024 + threadIdx.x; src = srcGu; dst = dstGu; }
    else              { i = (b - CONVB_GU) * 1024 + threadIdx.x; src = srcX; dst = dstXg; }
    float4 v = src[i];
    uint2 o; o.x = pack2(v.x, v.y); o.y = pack2(v.z, v.w);
    dst[i] = o;
    return;
  }
  // ---- routing: one 1024-thread block ----
  __shared__ int cnt[NE], offs[NE], cur[NE];
  const int tid = threadIdx.x, lane = tid & 63;
  for (int i = tid; i < MP; i += 1024) slot_token[i] = -1;
  if (tid < NE) cnt[tid] = 0;
  __syncthreads();
  int myE[8];
#pragma unroll
  for (int c = 0; c < 8; ++c) myE[c] = idx[c * 1024 + tid];
#pragma unroll
  for (int c = 0; c < 8; ++c) {
    int e = myE[c];
#pragma unroll
    for (int ex = 0; ex < NE; ++ex) {
      unsigned long long m = __ballot(e == ex);
      if (lane == 0 && m) atomicAdd(&cnt[ex], __popcll(m));
    }
  }
  __syncthreads();
  if (tid == 0) {
    int cum = 0;
    for (int e = 0; e < NE; ++e) {
      offs[e] = cum; cur[e] = 0;
      int nb = (cnt[e] + 127) >> 7;
      int bb = cum >> 7;
      for (int b = 0; b < nb; ++b) table[bb + b] = e;
      cum += nb << 7;
    }
    for (int b = cum >> 7; b < NBR; ++b) table[b] = -1;
  }
  __syncthreads();
#pragma unroll
  for (int c = 0; c < 8; ++c) {
    int e = myE[c];
    int pos = 0;
#pragma unroll
    for (int ex = 0; ex < NE; ++ex) {
      unsigned long long m = __ballot(e == ex);
      if (e == ex) {
        int rank = __popcll(m & ((1ull << lane) - 1ull));
        int leader = __ffsll(m) - 1;
        int base = 0;
        if (lane == leader) base = atomicAdd(&cur[ex], __popcll(m));
        base = __shfl(base, leader);
        pos = offs[ex] + base + rank;
      }
    }
    slot_token[pos] = (c * 1024 + tid) >> 1;
    tok2slot[c * 1024 + tid] = pos;
  }
}

__global__ void combine_kernel(const unsigned short* __restrict__ O0,
                               const unsigned short* __restrict__ O1,
                               const int* __restrict__ tok2slot,
                               const float* __restrict__ wts, float4* __restrict__ out) {
  int t = blockIdx.x, c = threadIdx.x;   // 4096 x 256; 4 cols/thread
  int s0 = tok2slot[2 * t], s1 = tok2slot[2 * t + 1];
  float w0 = wts[2 * t], w1 = wts[2 * t + 1];
  uint2 a0 = ((const uint2*)(O0 + (size_t)s0 * OUTD))[c];
  uint2 b0 = ((const uint2*)(O1 + (size_t)s0 * OUTD))[c];
  uint2 a1 = ((const uint2*)(O0 + (size_t)s1 * OUTD))[c];
  uint2 b1 = ((const uint2*)(O1 + (size_t)s1 * OUTD))[c];
  float4 o;
  o.x = w0 * (bf2f(a0.x & 0xFFFF) + bf2f(b0.x & 0xFFFF)) + w1 * (bf2f(a1.x & 0xFFFF) + bf2f(b1.x & 0xFFFF));
  o.y = w0 * (bf2f(a0.x >> 16)    + bf2f(b0.x >> 16))    + w1 * (bf2f(a1.x >> 16)    + bf2f(b1.x >> 16));
  o.z = w0 * (bf2f(a0.y & 0xFFFF) + bf2f(b0.y & 0xFFFF)) + w1 * (bf2f(a1.y & 0xFFFF) + bf2f(b1.y & 0xFFFF));
  o.w = w0 * (bf2f(a0.y >> 16)    + bf2f(b0.y >> 16))    + w1 * (bf2f(a1.y >> 16)    + bf2f(b1.y >> 16));
  out[(size_t)t * (OUTD / 4) + c] = o;
}

// ---------- GEMM1: h = silu(Xg*Wg^T) * (Xg*Wu^T), BK=64, 16x16x32, single-buffer ----------
// grid (40, 72): x<32 = GEMM tiles (A rows resolved slot->token); x>=32 = Wd convert
#define WD_N4 (NE * OUTD * HID / 4)     // 4194304 float4
#define CVT_NB 576                      // 8 x 72 convert blocks
__global__ __launch_bounds__(256) void gemm1_kernel(
    const unsigned short* __restrict__ Xg,   // [TOKS, DIM] token-major
    const unsigned short* __restrict__ Wgu,  // [NE, 2*HID, DIM]
    unsigned short* __restrict__ Hbuf,       // [MP, HID] slot-major
    const int* __restrict__ table,
    const int* __restrict__ slot_token,
    const float4* __restrict__ srcD, uint2* __restrict__ dstD) {
  if (blockIdx.x >= 32) {
    // ---- Wd convert, grid-stride over 4.2M float4 (~100MB traffic) ----
    const int cid = ((int)blockIdx.x - 32) + 8 * (int)blockIdx.y;   // 0..575
    const int NT = CVT_NB * 256;
    for (int i = cid * 256 + (int)threadIdx.x; i < WD_N4; i += NT) {
      float4 v = srcD[i];
      uint2 o; o.x = pack2(v.x, v.y); o.y = pack2(v.z, v.w);
      dstD[i] = o;
    }
    return;
  }
  int e = table[blockIdx.y];
  if (e < 0) return;
  const int tid = threadIdx.x;
  const int lane = tid & 63, wave = tid >> 6;
  const int wm = wave >> 1, wn = wave & 1;
  const int lr = lane & 15, quad = lane >> 4;

  __shared__ bf16 As[128 * 64];
  __shared__ bf16 Bg[64 * 64];
  __shared__ bf16 Bu[64 * 64];

  // slot->token row bases for the 4 rows this thread stages (kt-invariant)
  const int r0 = tid >> 3;                       // 0..31
  size_t abase[4];
#pragma unroll
  for (int i = 0; i < 4; ++i) {
    int t = slot_token[blockIdx.y * 128 + i * 32 + r0];
    if (t < 0) t = 0;                            // pad slot: alias token 0 (never combined)
    abase[i] = (size_t)t * DIM;
  }

  const unsigned short* Wg_base = Wgu + (size_t)e * 2 * HID * DIM + (size_t)(blockIdx.x * 64) * DIM;
  const unsigned short* Wu_base = Wg_base + (size_t)HID * DIM;

  f32x4 accg[4][2] = {}; f32x4 accu[4][2] = {};

  for (int kt = 0; kt < DIM / 64; ++kt) {   // 16 iters
    const int kb = kt * 64;
#pragma unroll
    for (int i = 0; i < 4; ++i) {
      int s = i * 256 + tid, row = s >> 3, pc = s & 7, gc = pc ^ (row & 7);
      cp16(Xg + abase[i] + kb + gc * 8, (void*)(As + row * 64 + pc * 8));
    }
#pragma unroll
    for (int i = 0; i < 2; ++i) {
      int s = i * 256 + tid, row = s >> 3, pc = s & 7, gc = pc ^ (row & 7);
      cp16(Wg_base + (size_t)row * DIM + kb + gc * 8, (void*)(Bg + row * 64 + pc * 8));
      cp16(Wu_base + (size_t)row * DIM + kb + gc * 8, (void*)(Bu + row * 64 + pc * 8));
    }
    __syncthreads();
#pragma unroll
    for (int ks = 0; ks < 2; ++ks) {
      bf16x8 a[4], bg[2], bu[2];
#pragma unroll
      for (int i = 0; i < 4; ++i) {
        int row = wm * 64 + i * 16 + lr;
        int pc = (ks * 4 + quad) ^ (row & 7);
        a[i] = *(const bf16x8*)(As + row * 64 + pc * 8);
      }
#pragma unroll
      for (int j = 0; j < 2; ++j) {
        int row = wn * 32 + j * 16 + lr;
        int pc = (ks * 4 + quad) ^ (row & 7);
        bg[j] = *(const bf16x8*)(Bg + row * 64 + pc * 8);
        bu[j] = *(const bf16x8*)(Bu + row * 64 + pc * 8);
      }
#pragma unroll
      for (int i = 0; i < 4; ++i)
#pragma unroll
        for (int j = 0; j < 2; ++j) {
          accg[i][j] = __builtin_amdgcn_mfma_f32_16x16x32_bf16(a[i], bg[j], accg[i][j], 0, 0, 0);
          accu[i][j] = __builtin_amdgcn_mfma_f32_16x16x32_bf16(a[i], bu[j], accu[i][j], 0, 0, 0);
        }
    }
    __syncthreads();
  }

  const int rowBase = blockIdx.y * 128 + wm * 64;
  const int colBase = blockIdx.x * 64 + wn * 32;
#pragma unroll
  for (int i = 0; i < 4; ++i)
#pragma unroll
    for (int r = 0; r < 4; ++r) {
      int row = rowBase + i * 16 + quad * 4 + r;
#pragma unroll
      for (int j = 0; j < 2; ++j) {
        float g = accg[i][j][r], u = accu[i][j][r];
        float s = g / (1.0f + __expf(-g));
        Hbuf[(size_t)row * HID + colBase + j * 16 + lr] = f2bf(s * u);
      }
    }
}

// ---------- GEMM2: O[kslice][slot] = H(kslice)*Wd^T, BK=64, 16x16x32, K-split x2 ----------
// grid (8, 72, 2)
__global__ __launch_bounds__(256) void gemm2_kernel(
    const unsigned short* __restrict__ Hbuf, // [MP, HID]
    const unsigned short* __restrict__ Wd,   // [NE, OUTD, HID]
    unsigned short* __restrict__ O0,         // [MP, OUTD] bf16 partial
    unsigned short* __restrict__ O1,
    const int* __restrict__ table) {
  int e = table[blockIdx.y];
  if (e < 0) return;
  const int tid = threadIdx.x;
  const int lane = tid & 63, wave = tid >> 6;
  const int wm = wave >> 1, wn = wave & 1;
  const int lr = lane & 15, quad = lane >> 4;
  const int kslice = blockIdx.z;

  __shared__ bf16 As[128 * 64];
  __shared__ bf16 Bs[128 * 64];

  const unsigned short* A_base = Hbuf + (size_t)blockIdx.y * 128 * HID + kslice * (HID / 2);
  const unsigned short* B_base = Wd + (size_t)e * OUTD * HID + (size_t)(blockIdx.x * 128) * HID
                               + kslice * (HID / 2);

  f32x4 acc[4][4] = {};

  for (int kt = 0; kt < (HID / 2) / 64; ++kt) {   // 16 iters
    const int kb = kt * 64;
#pragma unroll
    for (int i = 0; i < 4; ++i) {
      int s = i * 256 + tid, row = s >> 3, pc = s & 7, gc = pc ^ (row & 7);
      cp16(A_base + (size_t)row * HID + kb + gc * 8, (void*)(As + row * 64 + pc * 8));
      cp16(B_base + (size_t)row * HID + kb + gc * 8, (void*)(Bs + row * 64 + pc * 8));
    }
    __syncthreads();
#pragma unroll
    for (int ks = 0; ks < 2; ++ks) {
      bf16x8 a[4], b[4];
#pragma unroll
      for (int i = 0; i < 4; ++i) {
        int row = wm * 64 + i * 16 + lr;
        int pc = (ks * 4 + quad) ^ (row & 7);
        a[i] = *(const bf16x8*)(As + row * 64 + pc * 8);
      }
#pragma unroll
      for (int j = 0; j < 4; ++j) {
        int row = wn * 64 + j * 16 + lr;
        int pc = (ks * 4 + quad) ^ (row & 7);
        b[j] = *(const bf16x8*)(Bs + row * 64 + pc * 8);
      }
#pragma unroll
      for (int i = 0; i < 4; ++i)
#pragma unroll
        for (int j = 0; j < 4; ++j)
          acc[i][j] = __builtin_amdgcn_mfma_f32_16x16x32_bf16(a[i], b[j], acc[i][j], 0, 0, 0);
    }
    __syncthreads();
  }

  unsigned short* O = kslice ? O1 : O0;
  const int rowBase = blockIdx.y * 128 + wm * 64;
  const int colBase = blockIdx.x * 128 + wn * 64;
#pragma unroll
  for (int i = 0; i < 4; ++i)
#pragma unroll
    for (int r = 0; r < 4; ++r) {
      int row = rowBase + i * 16 + quad * 4 + r;
      unsigned short* Orow = O + (size_t)row * OUTD + colBase;
#pragma unroll
      for (int j = 0; j < 4; ++j)
        Orow[j * 16 + lr] = f2bf(acc[i][j][r]);
    }
}

extern "C" void kernel_launch(void* const* d_in, const int* in_sizes, int n_in,
                              void* d_out, int out_size, void* d_ws, size_t ws_size,
                              hipStream_t stream) {
  const float* X     = (const float*)d_in[0];
  const int*   idx   = (const int*)d_in[1];
  const float* wts   = (const float*)d_in[2];
  const float* WguF  = (const float*)d_in[3];
  const float* WdF   = (const float*)d_in[4];
  float* out = (float*)d_out;

  char* base = (char*)d_ws;
  unsigned short* Wgu = (unsigned short*)(base + WGU_OFF);
  unsigned short* Wd  = (unsigned short*)(base + WD_OFF);
  unsigned short* Xg  = (unsigned short*)(base + XG_OFF);
  unsigned short* Hb  = (unsigned short*)(base + H_OFF);
  unsigned short* O0  = (unsigned short*)(base + O0_OFF);   // alias Wgu (dead after gemm1)
  unsigned short* O1  = (unsigned short*)(base + O1_OFF);
  int* slot_token = (int*)(base + TK_OFF);
  int* table      = (int*)(base + META_OFF);
  int* tok2slot   = (int*)(base + T2S_OFF);

  route_conv_kernel<<<1 + CONVB_GU + CONVB_X, 1024, 0, stream>>>(idx, table, slot_token, tok2slot,
      (const float4*)WguF, (uint2*)Wgu, (const float4*)X, (uint2*)Xg);
  gemm1_kernel<<<dim3(40, NBR), 256, 0, stream>>>(Xg, Wgu, Hb, table, slot_token,
      (const float4*)WdF, (uint2*)Wd);
  gemm2_kernel<<<dim3(8, NBR, 2), 256, 0, stream>>>(Hb, Wd, O0, O1, table);
  combine_kernel<<<TOKS, 256, 0, stream>>>(O0, O1, tok2slot, wts, (float4*)out);
}